// Round 2
// baseline (778.405 us; speedup 1.0000x reference)
//
#include <hip/hip_runtime.h>
#include <hip/hip_bf16.h>

#define NUM_HEADS 16
#define DM 1024
#define DEPTH 64
#define BB 4
#define SS 1024
#define SL 1023            // S-1
#define M_ROWS (BB*SL)     // 4092

typedef __attribute__((ext_vector_type(8))) short short8;
typedef __attribute__((ext_vector_type(4))) float floatx4;

__device__ inline unsigned short f2bf(float f) {
  __hip_bfloat16 hb = __float2bfloat16(f);
  return *reinterpret_cast<unsigned short*>(&hb);
}
__device__ inline short8 ld_frag(const unsigned short* p) {
  return *reinterpret_cast<const short8*>(p);
}

// ---------------- GEMM: C[M x 1024] = A[M x 1024] * B[1024 x 1024] + bias ----
// block 256 = 4 waves in 2x2; wave tile 64m x 64n; K-step 32 with LDS-staged
// transposed B tile (bshT[n][k], bf16, b128 frag reads).
template <bool A_BF16, bool OUT_BF16>
__global__ __launch_bounds__(256) void gemm_bias(
    const void* __restrict__ Av, const float* __restrict__ B,
    const float* __restrict__ bias, void* __restrict__ Cv, int M)
{
  __shared__ unsigned short bshT[128][40];   // pad 40 u16 = 80 B rows (16B-aligned)
  const int tid = threadIdx.x;
  const int w = tid >> 6, lane = tid & 63, q4 = lane >> 4, l16 = lane & 15;
  const int wm = w >> 1, wn = w & 1;
  const int rb = blockIdx.y * 128 + wm * 64;
  const int cb = blockIdx.x * 128;
  const int wc = wn * 64;

  floatx4 acc[4][4];
  #pragma unroll
  for (int i = 0; i < 4; i++)
    #pragma unroll
    for (int j = 0; j < 4; j++) acc[i][j] = (floatx4){0.f,0.f,0.f,0.f};

  const int sn = tid & 127;
  const int sk = (tid >> 7) * 16;

  for (int k0 = 0; k0 < DM; k0 += 32) {
    __syncthreads();
    {
      const float* bp = B + (size_t)(k0 + sk) * DM + cb + sn;
      unsigned short tmp[16];
      #pragma unroll
      for (int j = 0; j < 16; j++) tmp[j] = f2bf(bp[(size_t)j * DM]);
      *(uint4*)&bshT[sn][sk]     = *(uint4*)&tmp[0];
      *(uint4*)&bshT[sn][sk + 8] = *(uint4*)&tmp[8];
    }
    __syncthreads();

    short8 af[4];
    #pragma unroll
    for (int i = 0; i < 4; i++) {
      int m = rb + i * 16 + l16;
      if (m < M) {
        if (A_BF16) {
          af[i] = ld_frag((const unsigned short*)Av + (size_t)m * DM + k0 + q4 * 8);
        } else {
          const float* ap = (const float*)Av + (size_t)m * DM + k0 + q4 * 8;
          float4 f0 = *(const float4*)ap;
          float4 f1 = *(const float4*)(ap + 4);
          short8 t;
          t[0]=f2bf(f0.x); t[1]=f2bf(f0.y); t[2]=f2bf(f0.z); t[3]=f2bf(f0.w);
          t[4]=f2bf(f1.x); t[5]=f2bf(f1.y); t[6]=f2bf(f1.z); t[7]=f2bf(f1.w);
          af[i] = t;
        }
      } else {
        af[i] = (short8){0,0,0,0,0,0,0,0};
      }
    }
    #pragma unroll
    for (int jn = 0; jn < 4; jn++) {
      short8 bf = ld_frag(&bshT[wc + jn * 16 + l16][q4 * 8]);
      #pragma unroll
      for (int i = 0; i < 4; i++)
        acc[i][jn] = __builtin_amdgcn_mfma_f32_16x16x32_bf16(af[i], bf, acc[i][jn], 0, 0, 0);
    }
  }

  #pragma unroll
  for (int jn = 0; jn < 4; jn++) {
    int col = cb + wc + jn * 16 + l16;
    float bb = bias[col];
    #pragma unroll
    for (int i = 0; i < 4; i++) {
      #pragma unroll
      for (int r = 0; r < 4; r++) {
        int m = rb + i * 16 + q4 * 4 + r;
        if (m < M) {
          float val = acc[i][jn][r] + bb;
          if (OUT_BF16) ((unsigned short*)Cv)[(size_t)m * DM + col] = f2bf(val);
          else          ((float*)Cv)[(size_t)m * DM + col] = val;
        }
      }
    }
  }
}

// ---------------- Attention ------------------------------------------------
// grid (16 q-tiles, 16 heads, 4 batch); block 256 = 4 waves, wave owns 16 q rows.
// Pass 1: S=QK^T (MFMA) -> p=exp(relu(s/8)+mask*-1e9) -> rowsums.
// Pass 2: recompute S, write att = p/rowsum (fp32), PV via MFMA (P through LDS).
__global__ __launch_bounds__(256) void attn_kernel(
    const float* __restrict__ Q, const float* __restrict__ Kg,
    const float* __restrict__ Mask, const unsigned short* __restrict__ VV,
    float* __restrict__ Att, unsigned short* __restrict__ Out2)
{
  const int qt = blockIdx.x, h = blockIdx.y, b = blockIdx.z;
  const int tid = threadIdx.x;
  const int w = tid >> 6, lane = tid & 63, q4 = lane >> 4, l16 = lane & 15;
  const int qi0 = qt * 64;
  const int qb = w * 16;

  __shared__ unsigned short qsh[64][72];     // [q][d]   (bf16, pad: 144 B rows)
  __shared__ unsigned short ksh[64][72];     // [key][d]
  __shared__ unsigned short vshT[64][72];    // [d][key] (transposed)
  __shared__ unsigned short psh[4][16][72];  // per-wave P [q][key]

  // stage Q tile (query row qi reads q[b][qi+1][h*64 + d])
  {
    int qr = tid >> 2, d0 = (tid & 3) * 16;
    int qi = qi0 + qr;
    unsigned short tmp[16];
    if (qi < SL) {
      const float* src = Q + ((size_t)b * SS + qi + 1) * DM + h * DEPTH + d0;
      #pragma unroll
      for (int j = 0; j < 16; j += 4) {
        float4 f = *(const float4*)(src + j);
        tmp[j+0]=f2bf(f.x); tmp[j+1]=f2bf(f.y); tmp[j+2]=f2bf(f.z); tmp[j+3]=f2bf(f.w);
      }
    } else {
      #pragma unroll
      for (int j = 0; j < 16; j++) tmp[j] = 0;
    }
    *(uint4*)&qsh[qr][d0]     = *(uint4*)&tmp[0];
    *(uint4*)&qsh[qr][d0 + 8] = *(uint4*)&tmp[8];
  }

  auto stageK = [&](int kt) {
    int kr = tid >> 2, d0 = (tid & 3) * 16;
    int kj = kt * 64 + kr;
    unsigned short tmp[16];
    if (kj < SL) {
      const float* src = Kg + ((size_t)b * SS + kj) * DM + h * DEPTH + d0;
      #pragma unroll
      for (int j = 0; j < 16; j += 4) {
        float4 f = *(const float4*)(src + j);
        tmp[j+0]=f2bf(f.x); tmp[j+1]=f2bf(f.y); tmp[j+2]=f2bf(f.z); tmp[j+3]=f2bf(f.w);
      }
    } else {
      #pragma unroll
      for (int j = 0; j < 16; j++) tmp[j] = 0;
    }
    *(uint4*)&ksh[kr][d0]     = *(uint4*)&tmp[0];
    *(uint4*)&ksh[kr][d0 + 8] = *(uint4*)&tmp[8];
  };

  auto stageV = [&](int kt) {   // vshT[d][key_local], bf16 source in ws
    int d = tid & 63, k16 = (tid >> 6) * 16;
    unsigned short tmp[16];
    #pragma unroll
    for (int j = 0; j < 16; j++) {
      int kj = kt * 64 + k16 + j;
      tmp[j] = (kj < SL) ? VV[((size_t)b * SL + kj) * DM + h * DEPTH + d] : (unsigned short)0;
    }
    *(uint4*)&vshT[d][k16]     = *(uint4*)&tmp[0];
    *(uint4*)&vshT[d][k16 + 8] = *(uint4*)&tmp[8];
  };

  __syncthreads();

  // ---- pass 1: rowsums ----
  float rsv[4] = {0.f, 0.f, 0.f, 0.f};
  for (int kt = 0; kt < 16; kt++) {
    __syncthreads();
    stageK(kt);
    __syncthreads();
    #pragma unroll
    for (int nt = 0; nt < 4; nt++) {
      floatx4 s = (floatx4){0.f,0.f,0.f,0.f};
      s = __builtin_amdgcn_mfma_f32_16x16x32_bf16(
            ld_frag(&qsh[qb + l16][q4*8]), ld_frag(&ksh[nt*16 + l16][q4*8]), s, 0,0,0);
      s = __builtin_amdgcn_mfma_f32_16x16x32_bf16(
            ld_frag(&qsh[qb + l16][32 + q4*8]), ld_frag(&ksh[nt*16 + l16][32 + q4*8]), s, 0,0,0);
      int kj = kt * 64 + nt * 16 + l16;
      bool kv = kj < SL;
      int qi_b = qi0 + qb + q4 * 4;
      const float* mp = Mask + ((size_t)b * SL + qi_b) * SL + kj;
      #pragma unroll
      for (int r = 0; r < 4; r++) {
        int qi = qi_b + r;
        float mval = (kv && qi < SL) ? mp[(size_t)r * SL] : 0.f;
        float sv = fmaxf(s[r] * 0.125f, 0.f) + mval * (-1e9f);
        float p = kv ? __expf(sv) : 0.f;
        rsv[r] += p;
      }
    }
  }
  #pragma unroll
  for (int r = 0; r < 4; r++) {
    #pragma unroll
    for (int off = 1; off < 16; off <<= 1) rsv[r] += __shfl_xor(rsv[r], off, 64);
  }
  float inv[4];
  #pragma unroll
  for (int r = 0; r < 4; r++) inv[r] = 1.f / rsv[r];

  // ---- pass 2: att + PV ----
  floatx4 oacc[4];
  #pragma unroll
  for (int i = 0; i < 4; i++) oacc[i] = (floatx4){0.f,0.f,0.f,0.f};

  for (int kt = 0; kt < 16; kt++) {
    __syncthreads();
    stageK(kt);
    stageV(kt);
    __syncthreads();
    #pragma unroll
    for (int nt = 0; nt < 4; nt++) {
      floatx4 s = (floatx4){0.f,0.f,0.f,0.f};
      s = __builtin_amdgcn_mfma_f32_16x16x32_bf16(
            ld_frag(&qsh[qb + l16][q4*8]), ld_frag(&ksh[nt*16 + l16][q4*8]), s, 0,0,0);
      s = __builtin_amdgcn_mfma_f32_16x16x32_bf16(
            ld_frag(&qsh[qb + l16][32 + q4*8]), ld_frag(&ksh[nt*16 + l16][32 + q4*8]), s, 0,0,0);
      int kj = kt * 64 + nt * 16 + l16;
      bool kv = kj < SL;
      int qi_b = qi0 + qb + q4 * 4;
      const float* mp = Mask + ((size_t)b * SL + qi_b) * SL + kj;
      #pragma unroll
      for (int r = 0; r < 4; r++) {
        int qi = qi_b + r;
        bool qv = qi < SL;
        float mval = (kv && qv) ? mp[(size_t)r * SL] : 0.f;
        float sv = fmaxf(s[r] * 0.125f, 0.f) + mval * (-1e9f);
        float p = kv ? __expf(sv) : 0.f;
        float pn = p * inv[r];
        if (kv && qv)
          Att[(((size_t)(b * NUM_HEADS + h)) * SL + qi) * SL + kj] = pn;
        psh[w][q4 * 4 + r][nt * 16 + l16] = f2bf(pn);
      }
    }
    // PV: oacc(16q x 64d) += P(16q x 64k) @ V(64k x 64d)
    short8 pa0 = ld_frag(&psh[w][l16][q4 * 8]);
    short8 pa1 = ld_frag(&psh[w][l16][32 + q4 * 8]);
    #pragma unroll
    for (int nt2 = 0; nt2 < 4; nt2++) {
      oacc[nt2] = __builtin_amdgcn_mfma_f32_16x16x32_bf16(
                    pa0, ld_frag(&vshT[nt2*16 + l16][q4*8]), oacc[nt2], 0,0,0);
      oacc[nt2] = __builtin_amdgcn_mfma_f32_16x16x32_bf16(
                    pa1, ld_frag(&vshT[nt2*16 + l16][32 + q4*8]), oacc[nt2], 0,0,0);
    }
  }

  #pragma unroll
  for (int nt2 = 0; nt2 < 4; nt2++) {
    #pragma unroll
    for (int r = 0; r < 4; r++) {
      int qi = qi0 + qb + q4 * 4 + r;
      if (qi < SL)
        Out2[((size_t)b * SL + qi) * DM + h * DEPTH + nt2 * 16 + l16] = f2bf(oacc[nt2][r]);
    }
  }
}

extern "C" void kernel_launch(void* const* d_in, const int* in_sizes, int n_in,
                              void* d_out, int out_size, void* d_ws, size_t ws_size,
                              hipStream_t stream) {
  const float* v    = (const float*)d_in[0];
  const float* k    = (const float*)d_in[1];
  const float* q    = (const float*)d_in[2];
  const float* mask = (const float*)d_in[3];
  const float* Wv   = (const float*)d_in[4];
  const float* bv   = (const float*)d_in[5];
  const float* Wd   = (const float*)d_in[6];
  const float* bd   = (const float*)d_in[7];

  float* out = (float*)d_out;                                  // (4,1023,1024) fp32
  float* att = out + (size_t)M_ROWS * DM;                      // (4,16,1023,1023) fp32
  unsigned short* vv   = (unsigned short*)d_ws;                // bf16 (4,1023,1024)
  unsigned short* out2 = vv + (size_t)M_ROWS * DM;             // bf16 (4,1023,1024)

  // vv = v @ Wv + bv   (fp32 A -> bf16 out in ws)
  gemm_bias<false, true><<<dim3(DM/128, (M_ROWS+127)/128), 256, 0, stream>>>(
      (const void*)v, Wv, bv, (void*)vv, M_ROWS);
  // attention: att (fp32, d_out) + out2 (bf16, ws)
  attn_kernel<<<dim3(16, NUM_HEADS, BB), 256, 0, stream>>>(q, k, mask, vv, att, out2);
  // out = out2 @ Wd + bd  (bf16 A -> fp32 out)
  gemm_bias<true, false><<<dim3(DM/128, (M_ROWS+127)/128), 256, 0, stream>>>(
      (const void*)out2, Wd, bd, (void*)out, M_ROWS);
}